// Round 21
// baseline (63.743 us; speedup 1.0000x reference)
//
#include <hip/hip_runtime.h>
#include <hip/hip_bf16.h>
#include <stdint.h>

// Recommender: B=4096 users, L=200 history, D=64 emb, F=100000 films.
// Kernel A (stats): 2048 FULLY-RESIDENT 256-thread blocks (8/CU x 256 CU);
//   each block processes users b and b+2048 sequentially -> no second
//   dispatch round, CU work self-averages over 16 users, tail = ~1 user.
//   Per user: 4 lanes per dim (d=t>>2, sub=t&3), DEPTH-2 software pipeline
//   (ping-pong peA/evA <-> peB/evB) so one group's LDS+VMEM loads are in
//   flight under the previous group's consume. pair_s padded to 224 with
//   {row0, weight 0.0}. Verified math verbatim (absmax 0, rounds 5-20):
//   dual 16x16 XS bit-transpose, plane-space sign fix, alive masks,
//   quad-DPP popc select, bucket-midpoint decode.
// Kernel B: tiny MLP 320->128->64->1 + sigmoid, 8 users/block (round-18).

#define B_ 4096
#define L_ 200
#define D_ 64
#define LPAD 224
#define GRID_ 2048

__device__ __forceinline__ void xpose_sign(uint32_t (&W)[16]) {
  // dual 16x16 bit-matrix transpose (verified): plane of raw key-bit bb is
  // W[15-bb]; key s (within chunk) at plane bit (15-(s>>1)) + 16*(s&1).
  #define XS(k, jj, m) { uint32_t tt = ((W[k] ^ (W[(k)|(jj)] >> (jj))) & (m)); \
                         W[k] ^= tt; W[(k)|(jj)] ^= (tt << (jj)); }
  XS(0,8,0x00FF00FFu) XS(1,8,0x00FF00FFu) XS(2,8,0x00FF00FFu) XS(3,8,0x00FF00FFu)
  XS(4,8,0x00FF00FFu) XS(5,8,0x00FF00FFu) XS(6,8,0x00FF00FFu) XS(7,8,0x00FF00FFu)
  XS(0,4,0x0F0F0F0Fu) XS(1,4,0x0F0F0F0Fu) XS(2,4,0x0F0F0F0Fu) XS(3,4,0x0F0F0F0Fu)
  XS(8,4,0x0F0F0F0Fu) XS(9,4,0x0F0F0F0Fu) XS(10,4,0x0F0F0F0Fu) XS(11,4,0x0F0F0F0Fu)
  XS(0,2,0x33333333u) XS(1,2,0x33333333u) XS(4,2,0x33333333u) XS(5,2,0x33333333u)
  XS(8,2,0x33333333u) XS(9,2,0x33333333u) XS(12,2,0x33333333u) XS(13,2,0x33333333u)
  XS(0,1,0x55555555u) XS(2,1,0x55555555u) XS(4,1,0x55555555u) XS(6,1,0x55555555u)
  XS(8,1,0x55555555u) XS(10,1,0x55555555u) XS(12,1,0x55555555u) XS(14,1,0x55555555u)
  #undef XS
  // sortable-key transform in plane space: key15 = ~sign; key_b = raw_b ^ sign
  const uint32_t S = W[0];                   // raw bit15 (sign) plane
  W[0] = ~S;
  #pragma unroll
  for (int j = 1; j < 16; ++j) W[j] ^= S;
}

template<bool TWO>
__device__ __forceinline__ uint32_t select_med(
    const uint32_t (&W0)[16], const uint32_t (&W1x)[16],
    uint32_t a0, uint32_t a1, int k)
{
  uint32_t prefix = 0;
  #pragma unroll
  for (int bb = 15; bb >= 0; --bb) {
    const uint32_t z0 = a0 & ~W0[15 - bb];   // zero-side keys, chunk 0
    int cnt = __popc(z0);
    uint32_t z1 = 0u;
    if (TWO) {
      z1 = a1 & ~W1x[15 - bb];
      cnt += __popc(z1);
    }
    // sum across the 4 sub-lanes of this dim: quad_perm xor1 then xor2 (VALU)
    cnt += __builtin_amdgcn_update_dpp(0, cnt, 0xB1, 0xF, 0xF, true); // [1,0,3,2]
    cnt += __builtin_amdgcn_update_dpp(0, cnt, 0x4E, 0xF, 0xF, true); // [2,3,0,1]
    const bool zs = (k < cnt);
    a0 = zs ? z0 : (a0 ^ z0);
    if (TWO) a1 = zs ? z1 : (a1 ^ z1);
    k      = zs ? k : (k - cnt);
    prefix = zs ? prefix : (prefix | (1u << bb));
  }
  return prefix;
}

__global__ __launch_bounds__(256) void stats_kernel(
    const int* __restrict__ film_hist,
    const float* __restrict__ ratings,
    const int* __restrict__ lengths,
    const int* __restrict__ film_indices,
    const float* __restrict__ emb,
    float* __restrict__ x)
{
  __shared__ uint2 pair_s[LPAD];             // {h<<8, weight bits}; pad {0,0}
  __shared__ float red[4];
  __shared__ float ue[4*D_];                 // [min|max|mean|med]

  const int t = threadIdx.x;
  const int wv = t >> 6;
  const int lane = t & 63;
  const int d = t >> 2;                      // dim 0..63
  const int sub = t & 3;
  const char* eb = (const char*)emb;
  const uint32_t d4 = (uint32_t)d * 4u;

  #pragma unroll 1
  for (int u = 0; u < 2; ++u) {
    const int b = blockIdx.x + GRID_ * u;
    const int n = lengths[b];                // block-uniform
    __syncthreads();                         // (0) protect pair_s/red reuse

    // film embedding (issued early; written at the end by t<64)
    const int fi = film_indices[b];
    const float fev = (t < 64) ? emb[(size_t)fi * D_ + t] : 0.f;

    // ---- stage {h<<8, rating}, pad [n,224) with {row0, 0.0}; mean ----
    float r = 0.f;
    if (t < LPAD) {
      uint2 e;
      if (t < n) {
        e.x = ((uint32_t)film_hist[(size_t)b*L_ + t]) << 8;  // emb byte offset
        r = ratings[(size_t)b*L_ + t];
        e.y = __float_as_uint(r);
      } else {
        e.x = 0u; e.y = 0u;                  // pad: row 0, weight 0.0
      }
      pair_s[t] = e;
    }
    float s = r;
    #pragma unroll
    for (int off = 32; off; off >>= 1) s += __shfl_down(s, off);
    if (lane == 0) red[wv] = s;
    __syncthreads();                         // (1) staging + mean partials
    const float mr1 = 0.1f - (red[0]+red[1]+red[2]+red[3]) / (float)n;

    // pre-fold weight = rating + mr1 (pad keeps weight 0.0)
    if (t < n) pair_s[t].y = __float_as_uint(r + mr1);
    __syncthreads();                         // (2) weights ready

    // ---- depth-2 pipelined gather + stats + key pack ----
    float vmin = __builtin_inff(), vmax = -__builtin_inff(), vsum = 0.f;
    uint32_t W0[16], W1x[16];
    #pragma unroll
    for (int j = 0; j < 16; ++j) { W0[j] = 0u; W1x[j] = 0u; }

    const int ng    = (n + 15) >> 4;         // 1..13, block-uniform
    const int nfull = n >> 4;                // mask-free groups

    #define LDSP(G, PE) { \
      _Pragma("unroll") \
      for (int j = 0; j < 4; ++j) PE[j] = pair_s[sub + 16*(G) + 4*j]; }
    #define VMEMG(PE, EV) { \
      _Pragma("unroll") \
      for (int j = 0; j < 4; ++j) \
        EV[j] = *(const float*)(eb + (PE[j].x + d4)); }
    #define CONSG(G, EV, PE) { \
      uint32_t kk[4]; \
      _Pragma("unroll") \
      for (int j = 0; j < 4; ++j) { \
        const float w_ = EV[j] * __uint_as_float(PE[j].y); \
        vsum += w_;                    /* pad weight 0 -> contributes 0 */ \
        kk[j] = __float_as_uint(w_); \
      } \
      if ((G) < nfull) { \
        _Pragma("unroll") \
        for (int j = 0; j < 4; ++j) { \
          const float w_ = __uint_as_float(kk[j]); \
          vmin = fminf(vmin, w_); vmax = fmaxf(vmax, w_); \
        } \
      } else { \
        _Pragma("unroll") \
        for (int j = 0; j < 4; ++j) { \
          const int l_ = sub + 16*(G) + 4*j; \
          const float w_ = __uint_as_float(kk[j]); \
          vmin = fminf(vmin, (l_ < n) ? w_ :  __builtin_inff()); \
          vmax = fmaxf(vmax, (l_ < n) ? w_ : -__builtin_inff()); \
        } \
      } \
      const uint32_t wA_ = __builtin_amdgcn_perm(kk[1], kk[0], 0x07060302u); \
      const uint32_t wB_ = __builtin_amdgcn_perm(kk[3], kk[2], 0x07060302u); \
      if ((G) < 8) { W0[2*(G)]       = wA_; W0[2*(G)+1]       = wB_; } \
      else         { W1x[2*((G)-8)]  = wA_; W1x[2*((G)-8)+1]  = wB_; } }

    uint2 peA[4], peB[4];
    float evA[4], evB[4];
    LDSP(0, peA); VMEMG(peA, evA);           // prologue
    #pragma unroll
    for (int gp = 0; gp < 7; ++gp) {
      const int g = 2*gp;
      if (g < ng) {                          // block-uniform guards
        if (g+1 < ng) { LDSP(g+1, peB); VMEMG(peB, evB); }
        CONSG(g, evA, peA);
        if (g+2 < ng) { LDSP(g+2, peA); VMEMG(peA, evA); }
        if (g+1 < ng) { CONSG(g+1, evB, peB); }
      }
    }
    #undef LDSP
    #undef VMEMG
    #undef CONSG

    // quad-reduce min/max/sum across the 4 subs
    vmin = fminf(vmin, __shfl_xor(vmin, 1));
    vmin = fminf(vmin, __shfl_xor(vmin, 2));
    vmax = fmaxf(vmax, __shfl_xor(vmax, 1));
    vmax = fmaxf(vmax, __shfl_xor(vmax, 2));
    vsum += __shfl_xor(vsum, 1);
    vsum += __shfl_xor(vsum, 2);

    // transpose + sign-fix planes (chunk 1 only if any thread has >32 keys)
    const bool two = (n > 128);              // block-uniform
    xpose_sign(W0);
    if (two) xpose_sign(W1x);

    // alive masks (verified formula)
    const int cth = (n > sub) ? ((n - sub + 3) >> 2) : 0;   // <= 50
    const int v0 = (cth < 32) ? cth : 32;
    const int v1 = cth - v0;
    const int ce0 = (v0 + 1) >> 1, cf0 = v0 >> 1;
    uint32_t a0 = ((1u << ce0) - 1u) << (16 - ce0);
    if (cf0) a0 |= ((1u << cf0) - 1u) << (32 - cf0);
    const int ce1 = (v1 + 1) >> 1, cf1 = v1 >> 1;
    uint32_t a1 = ((1u << ce1) - 1u) << (16 - ce1);
    if (cf1) a1 |= ((1u << cf1) - 1u) << (32 - cf1);
    if (v1 == 0) a1 = 0u;

    // bit-serial popc median select
    const int k = (n - 1) >> 1;
    const uint32_t prefix = two ? select_med<true >(W0, W1x, a0, a1, k)
                                : select_med<false>(W0, W1x, a0, a1, k);

    if (sub == 0) {
      uint32_t key32 = (prefix << 16) | 0x8000u;         // bucket midpoint
      const float med = (prefix & 0x8000u) ? __uint_as_float(key32 ^ 0x80000000u)
                                           : __uint_as_float(~key32);
      ue[d]       = vmin;
      ue[64 + d]  = vmax;
      ue[128 + d] = vsum / (float)n;
      ue[192 + d] = med;
    }
    __syncthreads();                         // (3) ue complete

    // ---- L2-normalize ue, write x = [ue_norm(256) | fe(64)] ----
    const float vv = ue[t];
    float ss = vv * vv;
    #pragma unroll
    for (int off = 32; off; off >>= 1) ss += __shfl_down(ss, off);
    if (lane == 0) red[wv] = ss;
    __syncthreads();                         // (4) sumsq partials
    const float rn = 1.0f / sqrtf(red[0]+red[1]+red[2]+red[3]);

    float* xb = x + (size_t)b * 320;
    xb[t] = vv * rn;
    if (t < 64) xb[256 + t] = fev;
  }
}

#define U_ 8   // users per MLP block -> 512 blocks

__global__ __launch_bounds__(256) void mlp_kernel(
    const float* __restrict__ x,
    const float* __restrict__ W1, const float* __restrict__ b1,
    const float* __restrict__ W2, const float* __restrict__ b2,
    const float* __restrict__ W3, const float* __restrict__ b3,
    float* __restrict__ out)
{
  __shared__ float xs[U_*320];
  __shared__ float h1s[U_*128];
  __shared__ float h2s[U_*64];
  const int t = threadIdx.x;
  const int u0 = blockIdx.x * U_;

  for (int i = t; i < U_*80; i += 256)
    ((float4*)xs)[i] = ((const float4*)(x + (size_t)u0*320))[i];
  __syncthreads();

  // h1 = relu(x @ W1 + b1): 8 users x 128 out; thread = (j, 4-user group)
  {
    const int j = t & 127, g = t >> 7;
    const int ub = g*4;
    float acc[4];
    const float bj = b1[j];
    #pragma unroll
    for (int q = 0; q < 4; ++q) acc[q] = bj;
    for (int i = 0; i < 320; i += 4) {
      float w0 = W1[(i+0)*128 + j];
      float w1 = W1[(i+1)*128 + j];
      float w2 = W1[(i+2)*128 + j];
      float w3 = W1[(i+3)*128 + j];
      #pragma unroll
      for (int q = 0; q < 4; ++q) {
        float4 xv = *(const float4*)&xs[(ub+q)*320 + i];   // LDS broadcast in-wave
        acc[q] += xv.x*w0 + xv.y*w1 + xv.z*w2 + xv.w*w3;
      }
    }
    #pragma unroll
    for (int q = 0; q < 4; ++q) h1s[(ub+q)*128 + j] = fmaxf(acc[q], 0.f);
  }
  __syncthreads();

  // h2 = relu(h1 @ W2 + b2): 8 users x 64 out
  {
    const int j = t & 63, g = t >> 6;
    const int ub = g*2;
    float acc[2];
    const float bj = b2[j];
    acc[0] = bj; acc[1] = bj;
    for (int i = 0; i < 128; i += 4) {
      float w0 = W2[(i+0)*64 + j];
      float w1 = W2[(i+1)*64 + j];
      float w2 = W2[(i+2)*64 + j];
      float w3 = W2[(i+3)*64 + j];
      #pragma unroll
      for (int q = 0; q < 2; ++q) {
        float4 hv = *(const float4*)&h1s[(ub+q)*128 + i];
        acc[q] += hv.x*w0 + hv.y*w1 + hv.z*w2 + hv.w*w3;
      }
    }
    #pragma unroll
    for (int q = 0; q < 2; ++q) h2s[(ub+q)*64 + j] = fmaxf(acc[q], 0.f);
  }
  __syncthreads();

  // out = sigmoid(h2 @ W3 + b3)
  if (t < U_*4) {
    const int u = t >> 2, sub = t & 3;
    float a = 0.f;
    #pragma unroll
    for (int i = 0; i < 16; ++i) a += h2s[u*64 + sub*16 + i] * W3[sub*16 + i];
    a += __shfl_xor(a, 1);
    a += __shfl_xor(a, 2);
    if (sub == 0) out[u0 + u] = 1.f / (1.f + __expf(-(a + b3[0])));
  }
}

extern "C" void kernel_launch(void* const* d_in, const int* in_sizes, int n_in,
                              void* d_out, int out_size, void* d_ws, size_t ws_size,
                              hipStream_t stream) {
  const int*   film_hist = (const int*)d_in[0];
  const float* ratings   = (const float*)d_in[1];
  const int*   lengths   = (const int*)d_in[2];
  const int*   film_idx  = (const int*)d_in[3];
  const float* emb       = (const float*)d_in[4];
  const float* W1 = (const float*)d_in[5];
  const float* b1 = (const float*)d_in[6];
  const float* W2 = (const float*)d_in[7];
  const float* b2 = (const float*)d_in[8];
  const float* W3 = (const float*)d_in[9];
  const float* b3 = (const float*)d_in[10];

  float* xbuf = (float*)d_ws;                 // B*320 f32 = 5.24 MB
  float* outp = (float*)d_out;

  stats_kernel<<<GRID_, 256, 0, stream>>>(film_hist, ratings, lengths, film_idx, emb, xbuf);
  mlp_kernel<<<B_/U_, 256, 0, stream>>>(xbuf, W1, b1, W2, b2, W3, b3, outp);
}

// Round 22
// 51.487 us; speedup vs baseline: 1.2380x; 1.2380x over previous
//
#include <hip/hip_runtime.h>
#include <hip/hip_bf16.h>
#include <stdint.h>

// Recommender: B=4096 users, L=200 history, D=64 emb, F=100000 films.
// Kernel A (stats): round-18 exact (best measured, ~36us): one user per
//   256-thread block, 4 lanes per dim (d=t>>2, sub=t&3), DEPTH-2 software
//   pipeline (ping-pong peA/evA <-> peB/evB). pair_s padded to 224 with
//   {row0, weight 0.0}. Verified math verbatim (absmax 0, rounds 5-21):
//   dual 16x16 XS bit-transpose, plane-space sign fix, alive masks,
//   quad-DPP popc select, bucket-midpoint decode.
// Kernel B (MLP rewrite): 8 users/block, threads = (j, i-half) with 8
//   user-accumulators per thread -> each W1/W2 element loaded ONCE per block
//   (W1 traffic halved vs (j,user-group) split), inner loop = 1 coalesced
//   W-load + 8 broadcast LDS reads + 8 independent FMAs.

#define B_ 4096
#define L_ 200
#define D_ 64
#define LPAD 224

__device__ __forceinline__ void xpose_sign(uint32_t (&W)[16]) {
  // dual 16x16 bit-matrix transpose (verified): plane of raw key-bit bb is
  // W[15-bb]; key s (within chunk) at plane bit (15-(s>>1)) + 16*(s&1).
  #define XS(k, jj, m) { uint32_t tt = ((W[k] ^ (W[(k)|(jj)] >> (jj))) & (m)); \
                         W[k] ^= tt; W[(k)|(jj)] ^= (tt << (jj)); }
  XS(0,8,0x00FF00FFu) XS(1,8,0x00FF00FFu) XS(2,8,0x00FF00FFu) XS(3,8,0x00FF00FFu)
  XS(4,8,0x00FF00FFu) XS(5,8,0x00FF00FFu) XS(6,8,0x00FF00FFu) XS(7,8,0x00FF00FFu)
  XS(0,4,0x0F0F0F0Fu) XS(1,4,0x0F0F0F0Fu) XS(2,4,0x0F0F0F0Fu) XS(3,4,0x0F0F0F0Fu)
  XS(8,4,0x0F0F0F0Fu) XS(9,4,0x0F0F0F0Fu) XS(10,4,0x0F0F0F0Fu) XS(11,4,0x0F0F0F0Fu)
  XS(0,2,0x33333333u) XS(1,2,0x33333333u) XS(4,2,0x33333333u) XS(5,2,0x33333333u)
  XS(8,2,0x33333333u) XS(9,2,0x33333333u) XS(12,2,0x33333333u) XS(13,2,0x33333333u)
  XS(0,1,0x55555555u) XS(2,1,0x55555555u) XS(4,1,0x55555555u) XS(6,1,0x55555555u)
  XS(8,1,0x55555555u) XS(10,1,0x55555555u) XS(12,1,0x55555555u) XS(14,1,0x55555555u)
  #undef XS
  // sortable-key transform in plane space: key15 = ~sign; key_b = raw_b ^ sign
  const uint32_t S = W[0];                   // raw bit15 (sign) plane
  W[0] = ~S;
  #pragma unroll
  for (int j = 1; j < 16; ++j) W[j] ^= S;
}

template<bool TWO>
__device__ __forceinline__ uint32_t select_med(
    const uint32_t (&W0)[16], const uint32_t (&W1x)[16],
    uint32_t a0, uint32_t a1, int k)
{
  uint32_t prefix = 0;
  #pragma unroll
  for (int bb = 15; bb >= 0; --bb) {
    const uint32_t z0 = a0 & ~W0[15 - bb];   // zero-side keys, chunk 0
    int cnt = __popc(z0);
    uint32_t z1 = 0u;
    if (TWO) {
      z1 = a1 & ~W1x[15 - bb];
      cnt += __popc(z1);
    }
    // sum across the 4 sub-lanes of this dim: quad_perm xor1 then xor2 (VALU)
    cnt += __builtin_amdgcn_update_dpp(0, cnt, 0xB1, 0xF, 0xF, true); // [1,0,3,2]
    cnt += __builtin_amdgcn_update_dpp(0, cnt, 0x4E, 0xF, 0xF, true); // [2,3,0,1]
    const bool zs = (k < cnt);
    a0 = zs ? z0 : (a0 ^ z0);
    if (TWO) a1 = zs ? z1 : (a1 ^ z1);
    k      = zs ? k : (k - cnt);
    prefix = zs ? prefix : (prefix | (1u << bb));
  }
  return prefix;
}

__global__ __launch_bounds__(256) void stats_kernel(
    const int* __restrict__ film_hist,
    const float* __restrict__ ratings,
    const int* __restrict__ lengths,
    const int* __restrict__ film_indices,
    const float* __restrict__ emb,
    float* __restrict__ x)
{
  __shared__ uint2 pair_s[LPAD];             // {h<<8, weight bits}; pad {0,0}
  __shared__ float red[4];
  __shared__ float ue[4*D_];                 // [min|max|mean|med]

  const int t = threadIdx.x;
  const int wv = t >> 6;
  const int lane = t & 63;
  const int d = t >> 2;                      // dim 0..63
  const int sub = t & 3;
  const int b = blockIdx.x;
  const int n = lengths[b];                  // block-uniform

  // film embedding (issued early; written at the end by t<64)
  const int fi = film_indices[b];
  const float fev = (t < 64) ? emb[(size_t)fi * D_ + t] : 0.f;

  // ---- stage {h<<8, rating}, pad [n,224) with {row0, 0.0}; mean partials ----
  float r = 0.f;
  if (t < LPAD) {
    uint2 e;
    if (t < n) {
      e.x = ((uint32_t)film_hist[(size_t)b*L_ + t]) << 8;  // emb byte offset
      r = ratings[(size_t)b*L_ + t];
      e.y = __float_as_uint(r);
    } else {
      e.x = 0u; e.y = 0u;                    // pad: row 0, weight 0.0
    }
    pair_s[t] = e;
  }
  float s = r;
  #pragma unroll
  for (int off = 32; off; off >>= 1) s += __shfl_down(s, off);
  if (lane == 0) red[wv] = s;
  __syncthreads();                           // (1) staging + mean partials
  const float mr1 = 0.1f - (red[0]+red[1]+red[2]+red[3]) / (float)n;

  // pre-fold weight = rating + mr1 (pad keeps weight 0.0)
  if (t < n) pair_s[t].y = __float_as_uint(r + mr1);
  __syncthreads();                           // (2) weights ready

  // ---- depth-2 pipelined gather + stats + key pack ----
  const char* eb = (const char*)emb;
  const uint32_t d4 = (uint32_t)d * 4u;
  float vmin = __builtin_inff(), vmax = -__builtin_inff(), vsum = 0.f;
  uint32_t W0[16], W1x[16];
  #pragma unroll
  for (int j = 0; j < 16; ++j) { W0[j] = 0u; W1x[j] = 0u; }

  const int ng    = (n + 15) >> 4;           // 1..13, block-uniform
  const int nfull = n >> 4;                  // mask-free groups

  #define LDSP(G, PE) { \
    _Pragma("unroll") \
    for (int j = 0; j < 4; ++j) PE[j] = pair_s[sub + 16*(G) + 4*j]; }
  #define VMEMG(PE, EV) { \
    _Pragma("unroll") \
    for (int j = 0; j < 4; ++j) \
      EV[j] = *(const float*)(eb + (PE[j].x + d4)); }
  #define CONSG(G, EV, PE) { \
    uint32_t kk[4]; \
    _Pragma("unroll") \
    for (int j = 0; j < 4; ++j) { \
      const float w_ = EV[j] * __uint_as_float(PE[j].y); \
      vsum += w_;                      /* pad weight 0 -> contributes 0 */ \
      kk[j] = __float_as_uint(w_); \
    } \
    if ((G) < nfull) { \
      _Pragma("unroll") \
      for (int j = 0; j < 4; ++j) { \
        const float w_ = __uint_as_float(kk[j]); \
        vmin = fminf(vmin, w_); vmax = fmaxf(vmax, w_); \
      } \
    } else { \
      _Pragma("unroll") \
      for (int j = 0; j < 4; ++j) { \
        const int l_ = sub + 16*(G) + 4*j; \
        const float w_ = __uint_as_float(kk[j]); \
        vmin = fminf(vmin, (l_ < n) ? w_ :  __builtin_inff()); \
        vmax = fmaxf(vmax, (l_ < n) ? w_ : -__builtin_inff()); \
      } \
    } \
    const uint32_t wA_ = __builtin_amdgcn_perm(kk[1], kk[0], 0x07060302u); \
    const uint32_t wB_ = __builtin_amdgcn_perm(kk[3], kk[2], 0x07060302u); \
    if ((G) < 8) { W0[2*(G)]       = wA_; W0[2*(G)+1]       = wB_; } \
    else         { W1x[2*((G)-8)]  = wA_; W1x[2*((G)-8)+1]  = wB_; } }

  uint2 peA[4], peB[4];
  float evA[4], evB[4];
  LDSP(0, peA); VMEMG(peA, evA);             // prologue
  #pragma unroll
  for (int gp = 0; gp < 7; ++gp) {
    const int g = 2*gp;
    if (g < ng) {                            // block-uniform guards throughout
      if (g+1 < ng) { LDSP(g+1, peB); VMEMG(peB, evB); }  // in flight over CONS(g)
      CONSG(g, evA, peA);
      if (g+2 < ng) { LDSP(g+2, peA); VMEMG(peA, evA); }  // in flight over CONS(g+1)
      if (g+1 < ng) { CONSG(g+1, evB, peB); }
    }
  }
  #undef LDSP
  #undef VMEMG
  #undef CONSG

  // quad-reduce min/max/sum across the 4 subs (one-time, shfl ok)
  vmin = fminf(vmin, __shfl_xor(vmin, 1));
  vmin = fminf(vmin, __shfl_xor(vmin, 2));
  vmax = fmaxf(vmax, __shfl_xor(vmax, 1));
  vmax = fmaxf(vmax, __shfl_xor(vmax, 2));
  vsum += __shfl_xor(vsum, 1);
  vsum += __shfl_xor(vsum, 2);

  // transpose + sign-fix planes (chunk 1 only if any thread has >32 keys)
  const bool two = (n > 128);                // block-uniform
  xpose_sign(W0);
  if (two) xpose_sign(W1x);

  // alive masks (verified formula; v = valid keys of this thread per chunk)
  const int cth = (n > sub) ? ((n - sub + 3) >> 2) : 0;   // <= 50
  const int v0 = (cth < 32) ? cth : 32;
  const int v1 = cth - v0;
  const int ce0 = (v0 + 1) >> 1, cf0 = v0 >> 1;
  uint32_t a0 = ((1u << ce0) - 1u) << (16 - ce0);
  if (cf0) a0 |= ((1u << cf0) - 1u) << (32 - cf0);
  const int ce1 = (v1 + 1) >> 1, cf1 = v1 >> 1;
  uint32_t a1 = ((1u << ce1) - 1u) << (16 - ce1);
  if (cf1) a1 |= ((1u << cf1) - 1u) << (32 - cf1);
  if (v1 == 0) a1 = 0u;

  // bit-serial popc median select (k-th smallest over the dim's n keys)
  const int k = (n - 1) >> 1;
  const uint32_t prefix = two ? select_med<true >(W0, W1x, a0, a1, k)
                              : select_med<false>(W0, W1x, a0, a1, k);

  if (sub == 0) {
    uint32_t key32 = (prefix << 16) | 0x8000u;           // bucket midpoint
    const float med = (prefix & 0x8000u) ? __uint_as_float(key32 ^ 0x80000000u)
                                         : __uint_as_float(~key32);
    ue[d]       = vmin;
    ue[64 + d]  = vmax;
    ue[128 + d] = vsum / (float)n;
    ue[192 + d] = med;
  }
  __syncthreads();                           // (3) ue complete

  // ---- L2-normalize ue, write x = [ue_norm(256) | fe(64)] ----
  const float vv = ue[t];
  float ss = vv * vv;
  #pragma unroll
  for (int off = 32; off; off >>= 1) ss += __shfl_down(ss, off);
  if (lane == 0) red[wv] = ss;
  __syncthreads();                           // (4) sumsq partials
  const float rn = 1.0f / sqrtf(red[0]+red[1]+red[2]+red[3]);

  float* xb = x + (size_t)b * 320;
  xb[t] = vv * rn;
  if (t < 64) xb[256 + t] = fev;
}

#define U_ 8   // users per MLP block -> 512 blocks

__global__ __launch_bounds__(256) void mlp_kernel(
    const float* __restrict__ x,
    const float* __restrict__ W1, const float* __restrict__ b1,
    const float* __restrict__ W2, const float* __restrict__ b2,
    const float* __restrict__ W3, const float* __restrict__ b3,
    float* __restrict__ out)
{
  __shared__ float xs[U_*320];
  __shared__ float ph[2048];                 // partials: h1 2x(8x128), h2 4x(8x64)
  __shared__ float h1s[U_*128];
  __shared__ float h2s[U_*64];
  const int t = threadIdx.x;
  const int u0 = blockIdx.x * U_;

  for (int i = t; i < U_*80; i += 256)
    ((float4*)xs)[i] = ((const float4*)(x + (size_t)u0*320))[i];
  __syncthreads();

  // h1 partials: thread (j = t&127, ih = t>>7); each W1 element loaded ONCE
  // per block; 8 independent user-accumulators; xs reads are broadcasts.
  {
    const int j = t & 127, ih = t >> 7;
    const float* Wp = W1 + (size_t)(ih*160)*128 + j;
    const int xo = ih*160;
    float acc[8];
    #pragma unroll
    for (int u = 0; u < U_; ++u) acc[u] = 0.f;
    #pragma unroll 4
    for (int i = 0; i < 160; ++i) {
      const float w = Wp[(size_t)i*128];
      #pragma unroll
      for (int u = 0; u < U_; ++u) acc[u] += xs[u*320 + xo + i] * w;
    }
    #pragma unroll
    for (int u = 0; u < U_; ++u) ph[ih*1024 + u*128 + j] = acc[u];
  }
  __syncthreads();
  for (int e = t; e < 1024; e += 256) {      // h1 combine (8 users x 128)
    h1s[e] = fmaxf(b1[e & 127] + ph[e] + ph[1024 + e], 0.f);
  }
  __syncthreads();

  // h2 partials: thread (j2 = t&63, ih2 = t>>6); W2 element loaded once.
  {
    const int j2 = t & 63, ih2 = t >> 6;
    const float* Wp = W2 + (size_t)(ih2*32)*64 + j2;
    const int ho = ih2*32;
    float acc[8];
    #pragma unroll
    for (int u = 0; u < U_; ++u) acc[u] = 0.f;
    #pragma unroll 4
    for (int i = 0; i < 32; ++i) {
      const float w = Wp[(size_t)i*64];
      #pragma unroll
      for (int u = 0; u < U_; ++u) acc[u] += h1s[u*128 + ho + i] * w;
    }
    #pragma unroll
    for (int u = 0; u < U_; ++u) ph[ih2*512 + u*64 + j2] = acc[u];
  }
  __syncthreads();
  for (int e = t; e < 512; e += 256) {       // h2 combine (8 users x 64)
    h2s[e] = fmaxf(b2[e & 63] + ph[e] + ph[512 + e] + ph[1024 + e] + ph[1536 + e], 0.f);
  }
  __syncthreads();

  // out = sigmoid(h2 @ W3 + b3): u = t>>5, i = t&31; 32-lane shfl reduce
  {
    const int u = t >> 5, i = t & 31;
    float a = h2s[u*64 + i] * W3[i] + h2s[u*64 + 32 + i] * W3[32 + i];
    #pragma unroll
    for (int off = 16; off; off >>= 1) a += __shfl_xor(a, off);
    if (i == 0) out[u0 + u] = 1.f / (1.f + __expf(-(a + b3[0])));
  }
}

extern "C" void kernel_launch(void* const* d_in, const int* in_sizes, int n_in,
                              void* d_out, int out_size, void* d_ws, size_t ws_size,
                              hipStream_t stream) {
  const int*   film_hist = (const int*)d_in[0];
  const float* ratings   = (const float*)d_in[1];
  const int*   lengths   = (const int*)d_in[2];
  const int*   film_idx  = (const int*)d_in[3];
  const float* emb       = (const float*)d_in[4];
  const float* W1 = (const float*)d_in[5];
  const float* b1 = (const float*)d_in[6];
  const float* W2 = (const float*)d_in[7];
  const float* b2 = (const float*)d_in[8];
  const float* W3 = (const float*)d_in[9];
  const float* b3 = (const float*)d_in[10];

  float* xbuf = (float*)d_ws;                 // B*320 f32 = 5.24 MB
  float* outp = (float*)d_out;

  stats_kernel<<<B_, 256, 0, stream>>>(film_hist, ratings, lengths, film_idx, emb, xbuf);
  mlp_kernel<<<B_/U_, 256, 0, stream>>>(xbuf, W1, b1, W2, b2, W3, b3, outp);
}